// Round 13
// baseline (237.093 us; speedup 1.0000x reference)
//
#include <hip/hip_runtime.h>

#define MM 50000
#define EE 800000
#define C  64
#define NWIN (EE / 64)   // 12500 windows of 64 sorted edges
#define NPB  391         // ceil(50000/128) node-proj blocks (128 nodes each)
#define CNTB 3125        // count blocks (800000/256)
#define NSB  196         // scan blocks (196*256 = 50176)
#define LOG2E 1.44269504088896f

typedef _Float16 h2v __attribute__((ext_vector_type(2)));
typedef _Float16 f16x8 __attribute__((ext_vector_type(8)));
typedef float f32x4 __attribute__((ext_vector_type(4)));

union FU { unsigned int u[4]; f16x8 h; };
union RU { int i; h2v h; };

#if __has_builtin(__builtin_amdgcn_fdot2)
#define FDOT2(A, B, ACC) __builtin_amdgcn_fdot2((A), (B), (ACC), false)
#else
#define FDOT2(A, B, ACC) fmaf((float)(A).x, (float)(B).x, fmaf((float)(A).y, (float)(B).y, (ACC)))
#endif

// ---------- helpers ----------

__device__ __forceinline__ float fast_gelu(float x) {
    // x * sigmoid(1.5957691*(x+0.044715x^3)); exp folded to exp2 (coef *= log2e)
    float x3 = x * x * x;
    float u  = 2.3022082f * fmaf(0.044715f, x3, x);
    float ex = exp2f(-u);
    float s  = __builtin_amdgcn_rcpf(1.0f + ex);
    return x * s;
}

// ---------- kernel 1: node projections via MFMA, 128 nodes/block + fused count ----------
// W1, W2 pre-scaled by log2e during staging (w1h / w23h.x feed logits only).

__global__ __launch_bounds__(256) void node_proj_mfma(
    const float* __restrict__ feat,
    const float* __restrict__ W1, const float* __restrict__ W2,
    const float* __restrict__ W3,
    _Float16* __restrict__ w1h, h2v* __restrict__ w23h,
    const int* __restrict__ tgt, int* __restrict__ counts) {
    int bid = blockIdx.x;
    if (bid >= NPB) {  // fused edge-count blocks (no barrier taken on this path)
        int e = (bid - NPB) * 256 + threadIdx.x;
        if (e < EE) atomicAdd(&counts[tgt[e]], 1);
        return;
    }
    __shared__ _Float16 Asub[128][72];  // 18.4 KB
    __shared__ _Float16 Bt[192][72];    // 27.6 KB, transposed weights [col][k]
    int tid = threadIdx.x;

    {
        int row = tid >> 1, c0 = (tid & 1) * 32;
        int n = min(bid * 128 + row, MM - 1);
        const float4* s4 = (const float4*)(feat + (size_t)n * C + c0);
#pragma unroll
        for (int q = 0; q < 4; q++) {
            float4 fa = s4[2 * q], fb = s4[2 * q + 1];
            f16x8 v = {(_Float16)fa.x, (_Float16)fa.y, (_Float16)fa.z, (_Float16)fa.w,
                       (_Float16)fb.x, (_Float16)fb.y, (_Float16)fb.z, (_Float16)fb.w};
            *(f16x8*)&Asub[row][c0 + 8 * q] = v;
        }
    }
#pragma unroll
    for (int i = 0; i < 48; i++) {
        int idx = i * 256 + tid;
        int cc = idx & 63;
        int kk = (idx >> 6) & 63;
        int mat = idx >> 12;
        const float* W = (mat == 0) ? W1 : (mat == 1) ? W2 : W3;
        float w = W[kk * 64 + cc];
        if (mat < 2) w *= LOG2E;  // pre-scale logit projections for exp2
        Bt[mat * 64 + cc][kk] = (_Float16)w;
    }
    __syncthreads();

    int wv = tid >> 6, lane = tid & 63;
    int kgrp = (lane >> 4) * 8;
    f16x8 af0[2], af1[2];
#pragma unroll
    for (int rt2 = 0; rt2 < 2; rt2++) {
        int arow = wv * 32 + rt2 * 16 + (lane & 15);
        af0[rt2] = *(const f16x8*)&Asub[arow][kgrp];
        af1[rt2] = *(const f16x8*)&Asub[arow][32 + kgrp];
    }

    f32x4 acc[2][12];
#pragma unroll
    for (int rt2 = 0; rt2 < 2; rt2++)
#pragma unroll
        for (int ct = 0; ct < 12; ct++) acc[rt2][ct] = (f32x4){0.f, 0.f, 0.f, 0.f};

#pragma unroll
    for (int ct = 0; ct < 12; ct++) {
        int bcol = ct * 16 + (lane & 15);
        f16x8 b0 = *(const f16x8*)&Bt[bcol][kgrp];
        f16x8 b1 = *(const f16x8*)&Bt[bcol][32 + kgrp];
#pragma unroll
        for (int rt2 = 0; rt2 < 2; rt2++) {
            acc[rt2][ct] = __builtin_amdgcn_mfma_f32_16x16x32_f16(af0[rt2], b0, acc[rt2][ct], 0, 0, 0);
            acc[rt2][ct] = __builtin_amdgcn_mfma_f32_16x16x32_f16(af1[rt2], b1, acc[rt2][ct], 0, 0, 0);
        }
    }

    int cbase = lane & 15;
#pragma unroll
    for (int rt2 = 0; rt2 < 2; rt2++) {
#pragma unroll
        for (int reg = 0; reg < 4; reg++) {
            int n = bid * 128 + wv * 32 + rt2 * 16 + (lane >> 4) * 4 + reg;
            if (n < MM) {
#pragma unroll
                for (int ct = 0; ct < 4; ct++)
                    w1h[(size_t)n * C + ct * 16 + cbase] = (_Float16)acc[rt2][ct][reg];
#pragma unroll
                for (int ct = 0; ct < 4; ct++) {
                    h2v pv;
                    pv.x = (_Float16)acc[rt2][4 + ct][reg];   // w2 (scaled)
                    pv.y = (_Float16)acc[rt2][8 + ct][reg];   // w3 (unscaled)
                    w23h[(size_t)n * C + ct * 16 + cbase] = pv;
                }
            }
        }
    }
}

// ---------- hierarchical scan + const precompute (r11 form) ----------

__global__ __launch_bounds__(256) void scan1(const int* __restrict__ counts,
                                             int* __restrict__ offsets,
                                             int* __restrict__ bsum) {
    __shared__ int wsum[4];
    int tid = threadIdx.x;
    int lane = tid & 63, wv = tid >> 6;
    int i = blockIdx.x * 256 + tid;
    int orig = counts[i];
    int v = orig;
#pragma unroll
    for (int d = 1; d < 64; d <<= 1) {
        int u = __shfl_up(v, d);
        if (lane >= d) v += u;
    }
    if (lane == 63) wsum[wv] = v;
    __syncthreads();
    int woff = 0;
#pragma unroll
    for (int w = 0; w < 4; w++) woff += (w < wv) ? wsum[w] : 0;
    offsets[i] = woff + v - orig;  // block-local exclusive prefix
    if (tid == 255) bsum[blockIdx.x] = woff + v;
}

// scan of block sums + precompute of LN1 quadratic-form constants and Wd2 row sums.
// consts layout (floats): [0..5]=M00,M11,M22,M01,M02,M12; [6..8]=sum b*w; [9]=sum b^2;
// [10..12]=sum w; [13]=sum b; [14]=sum bd2; [16..47]=wsum2 as 32 h2v pairs.
__global__ __launch_bounds__(256) void scan2(int* __restrict__ bsum,
                                             const float* __restrict__ Wd1,
                                             const float* __restrict__ bd1,
                                             const float* __restrict__ Wd2,
                                             const float* __restrict__ bd2,
                                             float* __restrict__ consts) {
    __shared__ int wsum[4];
    int tid = threadIdx.x;
    int lane = tid & 63, wv = tid >> 6;
    int orig = (tid < NSB) ? bsum[tid] : 0;
    int v = orig;
#pragma unroll
    for (int d = 1; d < 64; d <<= 1) {
        int u = __shfl_up(v, d);
        if (lane >= d) v += u;
    }
    if (lane == 63) wsum[wv] = v;
    __syncthreads();
    int woff = 0;
#pragma unroll
    for (int w = 0; w < 4; w++) woff += (w < wv) ? wsum[w] : 0;
    if (tid < NSB) bsum[tid] = woff + v - orig;  // exclusive

    if (tid < 64) {
        int j = tid;
        float w0 = Wd1[j], w1 = Wd1[64 + j], w2 = Wd1[128 + j], b = bd1[j];
        float q[14] = {w0 * w0, w1 * w1, w2 * w2, w0 * w1, w0 * w2, w1 * w2,
                       b * w0, b * w1, b * w2, b * b, w0, w1, w2, b};
#pragma unroll
        for (int m = 1; m < 64; m <<= 1) {
#pragma unroll
            for (int k = 0; k < 14; k++) q[k] += __shfl_xor(q[k], m);
        }
        if (j == 0) {
#pragma unroll
            for (int k = 0; k < 14; k++) consts[k] = q[k];
        }
    } else if (tid < 128) {
        int k = tid - 64;
        float s = 0.f;
        const float4* r4 = (const float4*)(Wd2 + k * 64);
#pragma unroll
        for (int q4 = 0; q4 < 16; q4++) {
            float4 f = r4[q4];
            s += (f.x + f.y) + (f.z + f.w);
        }
        float sp = __shfl_xor(s, 1);
        if (!(k & 1)) {
            h2v pv;
            pv.x = (_Float16)s;
            pv.y = (_Float16)sp;
            ((h2v*)(consts + 16))[k >> 1] = pv;
        }
        float b = bd2[k];
#pragma unroll
        for (int m = 1; m < 64; m <<= 1) b += __shfl_xor(b, m);
        if (k == 0) consts[14] = b;
    }
}

__global__ __launch_bounds__(256) void scan3(int* __restrict__ offsets,
                                             const int* __restrict__ bsum,
                                             int* __restrict__ cursor) {
    int i = blockIdx.x * 256 + threadIdx.x;
    int o = offsets[i] + bsum[blockIdx.x];
    offsets[i] = o;
    cursor[i] = o;
}

// ---------- scatter: one 16B record per edge {src, tgt, f16(x0,x1), f16(x2)} ----------

__global__ __launch_bounds__(256) void scatter_kernel(
    const int* __restrict__ src, const int* __restrict__ tgt,
    const float* __restrict__ hood,
    int* __restrict__ cursor, int4* __restrict__ rec) {
    int e = blockIdx.x * 256 + threadIdx.x;
    if (e >= EE) return;
    int t = tgt[e];
    float x0 = hood[3 * e], x1 = hood[3 * e + 1], x2 = hood[3 * e + 2];
    int pos = atomicAdd(&cursor[t], 1);
    RU a, b;
    a.h.x = (_Float16)x0; a.h.y = (_Float16)x1;
    b.h.x = (_Float16)x2; b.h.y = (_Float16)0.f;
    rec[pos] = make_int4(src[e], t, a.i, b.i);
}

// ---------- main: r11 (proven 111 us) with exp2-domain logits ----------

union SMem {
    _Float16 wd2t[64][66];   // 8448 B, live only until bf[] hoisted to regs
    struct {
        h2v d2buf[4][64][33];  // 33792 B, per-wave h staging then final dv
        float mu2[4][64];      // 1024 B, per-edge pre-LN2 mean
    } s;
};

__global__ __launch_bounds__(256, 4) void main_kernel(
    const int4* __restrict__ rec, const int* __restrict__ offsets,
    const float* __restrict__ Wd1, const float* __restrict__ bd1,
    const float* __restrict__ g1, const float* __restrict__ b1,
    const float* __restrict__ Wd2, const float* __restrict__ bd2,
    const float* __restrict__ g2, const float* __restrict__ b2,
    const _Float16* __restrict__ w1h, const h2v* __restrict__ w23h,
    const float* __restrict__ cst,
    float* __restrict__ den, float* __restrict__ out) {
    __shared__ SMem sm;
    int tid = threadIdx.x;
    int wv = tid >> 6, lane = tid & 63;
    int p0 = blockIdx.x * 256 + wv * 64;
    int p = p0 + lane;

#pragma unroll
    for (int i = 0; i < 16; i++) {
        int idx = i * 256 + tid;
        int j = idx & 63, k = idx >> 6;
        sm.wd2t[j][k] = (_Float16)Wd2[k * 64 + j];
    }
    __syncthreads();

    f16x8 bf[8];
#pragma unroll
    for (int ct = 0; ct < 4; ct++) {
#pragma unroll
        for (int kh = 0; kh < 2; kh++) {
            const unsigned int* q =
                (const unsigned int*)&sm.wd2t[ct * 16 + (lane & 15)][kh * 32 + ((lane >> 4) << 3)];
            FU f;
            f.u[0] = q[0]; f.u[1] = q[1]; f.u[2] = q[2]; f.u[3] = q[3];
            bf[ct * 2 + kh] = f.h;
        }
    }
    float g2v[4], b2v[4], bd2v[4];
#pragma unroll
    for (int ct = 0; ct < 4; ct++) {
        g2v[ct]  = g2[ct * 16 + (lane & 15)];
        b2v[ct]  = b2[ct * 16 + (lane & 15)];
        bd2v[ct] = bd2[ct * 16 + (lane & 15)];
    }
    __syncthreads();  // all waves done reading wd2t; region becomes d2buf

    int4 rc = rec[p];
    int s_my = rc.x, t_my = rc.y;
    RU ra, rb;
    ra.i = rc.z; rb.i = rc.w;
    float x0 = (float)ra.h.x, x1 = (float)ra.h.y, x2 = (float)rb.h.x;

    // ---- LN1 stats via precomputed quadratic form ----
    float t01 = x0 * x1, t02 = x0 * x2, t12 = x1 * x2;
    float sA  = fmaf(x0, cst[10], fmaf(x1, cst[11], fmaf(x2, cst[12], cst[13])));
    float qqA = fmaf(x0 * x0, cst[0], fmaf(x1 * x1, cst[1], x2 * x2 * cst[2]));
    float qqB = fmaf(t01, cst[3], fmaf(t02, cst[4], t12 * cst[5]));
    float qqC = fmaf(x0, cst[6], fmaf(x1, cst[7], x2 * cst[8]));
    float sumsq = fmaf(2.f, qqB + qqC, qqA) + cst[9];
    float mu1 = sA * (1.0f / C);
    float var1 = fmaf(-mu1, mu1, sumsq * (1.0f / C));
    float rs1 = __builtin_amdgcn_rsqf(var1 + 1e-5f);

    // ---- pass B: compute h, LN1+GELU, f16 pairs -> own d2buf row; dot for mu2 ----
    const h2v* wsum2h = (const h2v*)(cst + 16);
    float dot = 0.f;
#pragma unroll
    for (int j2 = 0; j2 < 32; j2++) {
        int j = 2 * j2;
        float hp0 = fmaf(x0, Wd1[j], fmaf(x1, Wd1[C + j], fmaf(x2, Wd1[2 * C + j], bd1[j])));
        float hp1 = fmaf(x0, Wd1[j + 1],
                         fmaf(x1, Wd1[C + j + 1], fmaf(x2, Wd1[2 * C + j + 1], bd1[j + 1])));
        float t0 = fast_gelu(fmaf((hp0 - mu1) * rs1, g1[j], b1[j]));
        float t1 = fast_gelu(fmaf((hp1 - mu1) * rs1, g1[j + 1], b1[j + 1]));
        h2v hv;
        hv.x = (_Float16)t0;
        hv.y = (_Float16)t1;
        sm.s.d2buf[wv][lane][j2] = hv;
        dot = FDOT2(hv, wsum2h[j2], dot);
    }
    sm.s.mu2[wv][lane] = (dot + cst[14]) * (1.0f / C);
    __syncthreads();

    // ---- layer 2: per-wave 64x64x64 GEMM + LN2/GELU epilogue ----
#pragma unroll
    for (int rt = 0; rt < 4; rt++) {
        int arow = rt * 16 + (lane & 15);
        f16x8 af[2];
#pragma unroll
        for (int kh = 0; kh < 2; kh++) {
            const unsigned int* q =
                (const unsigned int*)&sm.s.d2buf[wv][arow][kh * 16 + ((lane >> 4) << 2)];
            FU f;
            f.u[0] = q[0]; f.u[1] = q[1]; f.u[2] = q[2]; f.u[3] = q[3];
            af[kh] = f.h;
        }
        f32x4 acc[4];
#pragma unroll
        for (int ct = 0; ct < 4; ct++) {
            f32x4 z = {0.f, 0.f, 0.f, 0.f};
            z = __builtin_amdgcn_mfma_f32_16x16x32_f16(af[0], bf[2 * ct], z, 0, 0, 0);
            z = __builtin_amdgcn_mfma_f32_16x16x32_f16(af[1], bf[2 * ct + 1], z, 0, 0, 0);
            acc[ct] = z;
        }
#pragma unroll
        for (int reg = 0; reg < 4; reg++) {
            float v0 = acc[0][reg] + bd2v[0];
            float v1 = acc[1][reg] + bd2v[1];
            float v2 = acc[2][reg] + bd2v[2];
            float v3 = acc[3][reg] + bd2v[3];
            float qq = fmaf(v0, v0, fmaf(v1, v1, fmaf(v2, v2, v3 * v3)));
#pragma unroll
            for (int m = 1; m <= 8; m <<= 1) qq += __shfl_xor(qq, m);
            int row = rt * 16 + ((lane >> 4) << 2) + reg;
            float mu = sm.s.mu2[wv][row];
            float var = fmaf(-mu, mu, qq * (1.0f / C));
            float rs = __builtin_amdgcn_rsqf(var + 1e-5f);
            float vv[4] = {v0, v1, v2, v3};
#pragma unroll
            for (int ct = 0; ct < 4; ct++) {
                float v = fast_gelu(fmaf((vv[ct] - mu) * rs, g2v[ct], b2v[ct]));
                float vp = __shfl_xor(v, 1);
                if (!(lane & 1)) {
                    h2v pv;
                    pv.x = (_Float16)v;
                    pv.y = (_Float16)vp;
                    sm.s.d2buf[wv][row][ct * 8 + ((lane & 15) >> 1)] = pv;
                }
            }
        }
    }
    __syncthreads();  // dv rows settled before cross-lane phase-2 reads

    // ---- phase 2: lane = channel; pipelined v23 gathers; w1 on segment change ----
    int cur_t = -1;
    bool owned = false;
    float den_a = 0.f, num_a = 0.f, w1v = 0.f;

    int tin[4];
    h2v v23n[4];
#define PREF(BASE)                                                             \
    {                                                                          \
        _Pragma("unroll")                                                      \
        for (int q = 0; q < 4; q++) {                                          \
            int sq = __shfl(s_my, (BASE) + q);                                 \
            tin[q] = __shfl(t_my, (BASE) + q);                                 \
            v23n[q] = w23h[(size_t)sq * C + lane];                             \
        }                                                                      \
    }
    PREF(0)
    for (int i0 = 0; i0 < 64; i0 += 4) {
        int tic[4];
        h2v v23c[4];
#pragma unroll
        for (int q = 0; q < 4; q++) { tic[q] = tin[q]; v23c[q] = v23n[q]; }
        if (i0 < 60) PREF(i0 + 4)
#pragma unroll
        for (int q = 0; q < 4; q++) {
            int i = i0 + q;
            int ti = tic[q];
            if (ti != cur_t) {
                if (cur_t >= 0) {
                    size_t o = (size_t)cur_t * C + lane;
                    if (owned) out[o] = num_a / den_a;
                    else { unsafeAtomicAdd(&den[o], den_a); unsafeAtomicAdd(&out[o], num_a); }
                }
                cur_t = ti; den_a = 0.f; num_a = 0.f;
                w1v = (float)w1h[(size_t)ti * C + lane];
                int o0 = offsets[ti], o1 = offsets[ti + 1];
                owned = (o0 >= p0) && (o1 <= p0 + 64);
            }
            h2v pr = sm.s.d2buf[wv][i][lane >> 1];
            float dv = (lane & 1) ? (float)pr.y : (float)pr.x;
            h2v v23 = v23c[q];
            float ee = exp2f(fmaf(dv, LOG2E, w1v) - (float)v23.x);
            den_a += ee;
            num_a = fmaf(ee, (float)v23.y + dv, num_a);
        }
    }
#undef PREF
    {
        size_t o = (size_t)cur_t * C + lane;
        if (owned) out[o] = num_a / den_a;
        else { unsafeAtomicAdd(&den[o], den_a); unsafeAtomicAdd(&out[o], num_a); }
    }
}

// ---------- finalize: divide straddler targets (den > 0) ----------

__global__ __launch_bounds__(256) void finalize(float4* __restrict__ out,
                                                const float4* __restrict__ den) {
    int i = blockIdx.x * 256 + threadIdx.x;
    if (i >= MM * (C / 4)) return;
    float4 dn = den[i];
    if (dn.x == 0.f && dn.y == 0.f && dn.z == 0.f && dn.w == 0.f) return;
    float4 nm = out[i];
    float4 o;
    o.x = (dn.x != 0.f) ? nm.x / dn.x : nm.x;
    o.y = (dn.y != 0.f) ? nm.y / dn.y : nm.y;
    o.z = (dn.z != 0.f) ? nm.z / dn.z : nm.z;
    o.w = (dn.w != 0.f) ? nm.w / dn.w : nm.w;
    out[i] = o;
}

// ---------- launch ----------

extern "C" void kernel_launch(void* const* d_in, const int* in_sizes, int n_in,
                              void* d_out, int out_size, void* d_ws, size_t ws_size,
                              hipStream_t stream) {
    const int*   src  = (const int*)d_in[0];
    const int*   tgt  = (const int*)d_in[1];
    const float* feat = (const float*)d_in[2];
    const float* hood = (const float*)d_in[3];
    const float* Wd1  = (const float*)d_in[4];
    const float* bd1  = (const float*)d_in[5];
    const float* g1   = (const float*)d_in[6];
    const float* b1   = (const float*)d_in[7];
    const float* Wd2  = (const float*)d_in[8];
    const float* bd2  = (const float*)d_in[9];
    const float* g2   = (const float*)d_in[10];
    const float* b2   = (const float*)d_in[11];
    const float* W1   = (const float*)d_in[12];
    const float* W2   = (const float*)d_in[13];
    const float* W3   = (const float*)d_in[14];

    char* ws = (char*)d_ws;
    int4*     rec  = (int4*)ws;              ws += (size_t)EE * 16;
    float*    den  = (float*)ws;             ws += (size_t)MM * C * 4;
    int* counts_cursor = (int*)ws;           ws += 50176 * 4;   // adjacent to den
    h2v*      w23h = (h2v*)ws;               ws += (size_t)MM * C * 4;
    _Float16* w1h  = (_Float16*)ws;          ws += (size_t)MM * C * 2;
    int* offsets = (int*)ws;                 ws += 50432 * 4;
    int* bsum = (int*)ws;                    ws += 256 * 4;
    float* consts = (float*)ws;
    float* out = (float*)d_out;

    // one memset covers den + counts (adjacent); out zeroed separately
    hipMemsetAsync(den, 0, (size_t)MM * C * 4 + 50176 * 4, stream);
    hipMemsetAsync(out, 0, (size_t)MM * C * sizeof(float), stream);

    node_proj_mfma<<<NPB + CNTB, 256, 0, stream>>>(feat, W1, W2, W3, w1h, w23h,
                                                   tgt, counts_cursor);
    scan1<<<NSB, 256, 0, stream>>>(counts_cursor, offsets, bsum);
    scan2<<<1, 256, 0, stream>>>(bsum, Wd1, bd1, Wd2, bd2, consts);
    scan3<<<NSB, 256, 0, stream>>>(offsets, bsum, counts_cursor);
    scatter_kernel<<<(EE + 255) / 256, 256, 0, stream>>>(src, tgt, hood,
                                                         counts_cursor, rec);
    main_kernel<<<NWIN / 4, 256, 0, stream>>>(rec, offsets,
                                              Wd1, bd1, g1, b1, Wd2, bd2, g2, b2,
                                              w1h, w23h, consts, den, out);
    finalize<<<(MM * 16 + 255) / 256, 256, 0, stream>>>((float4*)out, (const float4*)den);
}

// Round 14
// 220.554 us; speedup vs baseline: 1.0750x; 1.0750x over previous
//
#include <hip/hip_runtime.h>

#define MM 50000
#define EE 800000
#define C  64
#define NWIN (EE / 64)   // 12500 windows of 64 sorted edges
#define NPB  391         // ceil(50000/128) node-proj blocks (128 nodes each)
#define CNTB 3125        // count blocks (800000/256)
#define NSB  196         // scan blocks (196*256 = 50176)
#define LOG2E 1.44269504088896f

typedef _Float16 h2v __attribute__((ext_vector_type(2)));
typedef _Float16 f16x8 __attribute__((ext_vector_type(8)));
typedef float f32x4 __attribute__((ext_vector_type(4)));

union FU { unsigned int u[4]; f16x8 h; };
union RU { int i; h2v h; };

#if __has_builtin(__builtin_amdgcn_fdot2)
#define FDOT2(A, B, ACC) __builtin_amdgcn_fdot2((A), (B), (ACC), false)
#else
#define FDOT2(A, B, ACC) fmaf((float)(A).x, (float)(B).x, fmaf((float)(A).y, (float)(B).y, (ACC)))
#endif

// raw v_exp_f32 (D = 2^S0); libm exp2f is an OCML call with edge handling (r13 lesson)
#if __has_builtin(__builtin_amdgcn_exp2f)
#define EXP2F(X) __builtin_amdgcn_exp2f(X)
#else
#define EXP2F(X) __expf((X) * 0.6931471805599453f)
#endif

// ---------- helpers ----------

__device__ __forceinline__ float fast_gelu(float x) {
    // x * sigmoid(1.5957691*(x+0.044715x^3)); exp folded to exp2 (coef *= log2e)
    float x3 = x * x * x;
    float u  = 2.3022082f * fmaf(0.044715f, x3, x);
    float ex = EXP2F(-u);
    float s  = __builtin_amdgcn_rcpf(1.0f + ex);
    return x * s;
}

// ---------- kernel 1: node projections via MFMA, 128 nodes/block + fused count ----------
// W1, W2 pre-scaled by log2e during staging (w1h / w23h.x feed logits only).

__global__ __launch_bounds__(256) void node_proj_mfma(
    const float* __restrict__ feat,
    const float* __restrict__ W1, const float* __restrict__ W2,
    const float* __restrict__ W3,
    _Float16* __restrict__ w1h, h2v* __restrict__ w23h,
    const int* __restrict__ tgt, int* __restrict__ counts) {
    int bid = blockIdx.x;
    if (bid >= NPB) {  // fused edge-count blocks (no barrier taken on this path)
        int e = (bid - NPB) * 256 + threadIdx.x;
        if (e < EE) atomicAdd(&counts[tgt[e]], 1);
        return;
    }
    __shared__ _Float16 Asub[128][72];  // 18.4 KB
    __shared__ _Float16 Bt[192][72];    // 27.6 KB, transposed weights [col][k]
    int tid = threadIdx.x;

    {
        int row = tid >> 1, c0 = (tid & 1) * 32;
        int n = min(bid * 128 + row, MM - 1);
        const float4* s4 = (const float4*)(feat + (size_t)n * C + c0);
#pragma unroll
        for (int q = 0; q < 4; q++) {
            float4 fa = s4[2 * q], fb = s4[2 * q + 1];
            f16x8 v = {(_Float16)fa.x, (_Float16)fa.y, (_Float16)fa.z, (_Float16)fa.w,
                       (_Float16)fb.x, (_Float16)fb.y, (_Float16)fb.z, (_Float16)fb.w};
            *(f16x8*)&Asub[row][c0 + 8 * q] = v;
        }
    }
#pragma unroll
    for (int i = 0; i < 48; i++) {
        int idx = i * 256 + tid;
        int cc = idx & 63;
        int kk = (idx >> 6) & 63;
        int mat = idx >> 12;
        const float* W = (mat == 0) ? W1 : (mat == 1) ? W2 : W3;
        float w = W[kk * 64 + cc];
        if (mat < 2) w *= LOG2E;  // pre-scale logit projections for exp2
        Bt[mat * 64 + cc][kk] = (_Float16)w;
    }
    __syncthreads();

    int wv = tid >> 6, lane = tid & 63;
    int kgrp = (lane >> 4) * 8;
    f16x8 af0[2], af1[2];
#pragma unroll
    for (int rt2 = 0; rt2 < 2; rt2++) {
        int arow = wv * 32 + rt2 * 16 + (lane & 15);
        af0[rt2] = *(const f16x8*)&Asub[arow][kgrp];
        af1[rt2] = *(const f16x8*)&Asub[arow][32 + kgrp];
    }

    f32x4 acc[2][12];
#pragma unroll
    for (int rt2 = 0; rt2 < 2; rt2++)
#pragma unroll
        for (int ct = 0; ct < 12; ct++) acc[rt2][ct] = (f32x4){0.f, 0.f, 0.f, 0.f};

#pragma unroll
    for (int ct = 0; ct < 12; ct++) {
        int bcol = ct * 16 + (lane & 15);
        f16x8 b0 = *(const f16x8*)&Bt[bcol][kgrp];
        f16x8 b1 = *(const f16x8*)&Bt[bcol][32 + kgrp];
#pragma unroll
        for (int rt2 = 0; rt2 < 2; rt2++) {
            acc[rt2][ct] = __builtin_amdgcn_mfma_f32_16x16x32_f16(af0[rt2], b0, acc[rt2][ct], 0, 0, 0);
            acc[rt2][ct] = __builtin_amdgcn_mfma_f32_16x16x32_f16(af1[rt2], b1, acc[rt2][ct], 0, 0, 0);
        }
    }

    int cbase = lane & 15;
#pragma unroll
    for (int rt2 = 0; rt2 < 2; rt2++) {
#pragma unroll
        for (int reg = 0; reg < 4; reg++) {
            int n = bid * 128 + wv * 32 + rt2 * 16 + (lane >> 4) * 4 + reg;
            if (n < MM) {
#pragma unroll
                for (int ct = 0; ct < 4; ct++)
                    w1h[(size_t)n * C + ct * 16 + cbase] = (_Float16)acc[rt2][ct][reg];
#pragma unroll
                for (int ct = 0; ct < 4; ct++) {
                    h2v pv;
                    pv.x = (_Float16)acc[rt2][4 + ct][reg];   // w2 (scaled)
                    pv.y = (_Float16)acc[rt2][8 + ct][reg];   // w3 (unscaled)
                    w23h[(size_t)n * C + ct * 16 + cbase] = pv;
                }
            }
        }
    }
}

// ---------- hierarchical scan + const precompute (r11 form) ----------

__global__ __launch_bounds__(256) void scan1(const int* __restrict__ counts,
                                             int* __restrict__ offsets,
                                             int* __restrict__ bsum) {
    __shared__ int wsum[4];
    int tid = threadIdx.x;
    int lane = tid & 63, wv = tid >> 6;
    int i = blockIdx.x * 256 + tid;
    int orig = counts[i];
    int v = orig;
#pragma unroll
    for (int d = 1; d < 64; d <<= 1) {
        int u = __shfl_up(v, d);
        if (lane >= d) v += u;
    }
    if (lane == 63) wsum[wv] = v;
    __syncthreads();
    int woff = 0;
#pragma unroll
    for (int w = 0; w < 4; w++) woff += (w < wv) ? wsum[w] : 0;
    offsets[i] = woff + v - orig;  // block-local exclusive prefix
    if (tid == 255) bsum[blockIdx.x] = woff + v;
}

// scan of block sums + precompute of LN1 quadratic-form constants and Wd2 row sums.
// consts layout (floats): [0..5]=M00,M11,M22,M01,M02,M12; [6..8]=sum b*w; [9]=sum b^2;
// [10..12]=sum w; [13]=sum b; [14]=sum bd2; [16..47]=wsum2 as 32 h2v pairs.
__global__ __launch_bounds__(256) void scan2(int* __restrict__ bsum,
                                             const float* __restrict__ Wd1,
                                             const float* __restrict__ bd1,
                                             const float* __restrict__ Wd2,
                                             const float* __restrict__ bd2,
                                             float* __restrict__ consts) {
    __shared__ int wsum[4];
    int tid = threadIdx.x;
    int lane = tid & 63, wv = tid >> 6;
    int orig = (tid < NSB) ? bsum[tid] : 0;
    int v = orig;
#pragma unroll
    for (int d = 1; d < 64; d <<= 1) {
        int u = __shfl_up(v, d);
        if (lane >= d) v += u;
    }
    if (lane == 63) wsum[wv] = v;
    __syncthreads();
    int woff = 0;
#pragma unroll
    for (int w = 0; w < 4; w++) woff += (w < wv) ? wsum[w] : 0;
    if (tid < NSB) bsum[tid] = woff + v - orig;  // exclusive

    if (tid < 64) {
        int j = tid;
        float w0 = Wd1[j], w1 = Wd1[64 + j], w2 = Wd1[128 + j], b = bd1[j];
        float q[14] = {w0 * w0, w1 * w1, w2 * w2, w0 * w1, w0 * w2, w1 * w2,
                       b * w0, b * w1, b * w2, b * b, w0, w1, w2, b};
#pragma unroll
        for (int m = 1; m < 64; m <<= 1) {
#pragma unroll
            for (int k = 0; k < 14; k++) q[k] += __shfl_xor(q[k], m);
        }
        if (j == 0) {
#pragma unroll
            for (int k = 0; k < 14; k++) consts[k] = q[k];
        }
    } else if (tid < 128) {
        int k = tid - 64;
        float s = 0.f;
        const float4* r4 = (const float4*)(Wd2 + k * 64);
#pragma unroll
        for (int q4 = 0; q4 < 16; q4++) {
            float4 f = r4[q4];
            s += (f.x + f.y) + (f.z + f.w);
        }
        float sp = __shfl_xor(s, 1);
        if (!(k & 1)) {
            h2v pv;
            pv.x = (_Float16)s;
            pv.y = (_Float16)sp;
            ((h2v*)(consts + 16))[k >> 1] = pv;
        }
        float b = bd2[k];
#pragma unroll
        for (int m = 1; m < 64; m <<= 1) b += __shfl_xor(b, m);
        if (k == 0) consts[14] = b;
    }
}

__global__ __launch_bounds__(256) void scan3(int* __restrict__ offsets,
                                             const int* __restrict__ bsum,
                                             int* __restrict__ cursor) {
    int i = blockIdx.x * 256 + threadIdx.x;
    int o = offsets[i] + bsum[blockIdx.x];
    offsets[i] = o;
    cursor[i] = o;
}

// ---------- scatter: one 16B record per edge {src, tgt, f16(x0,x1), f16(x2)} ----------

__global__ __launch_bounds__(256) void scatter_kernel(
    const int* __restrict__ src, const int* __restrict__ tgt,
    const float* __restrict__ hood,
    int* __restrict__ cursor, int4* __restrict__ rec) {
    int e = blockIdx.x * 256 + threadIdx.x;
    if (e >= EE) return;
    int t = tgt[e];
    float x0 = hood[3 * e], x1 = hood[3 * e + 1], x2 = hood[3 * e + 2];
    int pos = atomicAdd(&cursor[t], 1);
    RU a, b;
    a.h.x = (_Float16)x0; a.h.y = (_Float16)x1;
    b.h.x = (_Float16)x2; b.h.y = (_Float16)0.f;
    rec[pos] = make_int4(src[e], t, a.i, b.i);
}

// ---------- main: r11 structure; exp2-domain logits via raw v_exp_f32 ----------

union SMem {
    _Float16 wd2t[64][66];   // 8448 B, live only until bf[] hoisted to regs
    struct {
        h2v d2buf[4][64][33];  // 33792 B, per-wave h staging then final dv
        float mu2[4][64];      // 1024 B, per-edge pre-LN2 mean
    } s;
};

__global__ __launch_bounds__(256, 4) void main_kernel(
    const int4* __restrict__ rec, const int* __restrict__ offsets,
    const float* __restrict__ Wd1, const float* __restrict__ bd1,
    const float* __restrict__ g1, const float* __restrict__ b1,
    const float* __restrict__ Wd2, const float* __restrict__ bd2,
    const float* __restrict__ g2, const float* __restrict__ b2,
    const _Float16* __restrict__ w1h, const h2v* __restrict__ w23h,
    const float* __restrict__ cst,
    float* __restrict__ den, float* __restrict__ out) {
    __shared__ SMem sm;
    int tid = threadIdx.x;
    int wv = tid >> 6, lane = tid & 63;
    int p0 = blockIdx.x * 256 + wv * 64;
    int p = p0 + lane;

#pragma unroll
    for (int i = 0; i < 16; i++) {
        int idx = i * 256 + tid;
        int j = idx & 63, k = idx >> 6;
        sm.wd2t[j][k] = (_Float16)Wd2[k * 64 + j];
    }
    __syncthreads();

    f16x8 bf[8];
#pragma unroll
    for (int ct = 0; ct < 4; ct++) {
#pragma unroll
        for (int kh = 0; kh < 2; kh++) {
            const unsigned int* q =
                (const unsigned int*)&sm.wd2t[ct * 16 + (lane & 15)][kh * 32 + ((lane >> 4) << 3)];
            FU f;
            f.u[0] = q[0]; f.u[1] = q[1]; f.u[2] = q[2]; f.u[3] = q[3];
            bf[ct * 2 + kh] = f.h;
        }
    }
    float g2v[4], b2v[4], bd2v[4];
#pragma unroll
    for (int ct = 0; ct < 4; ct++) {
        g2v[ct]  = g2[ct * 16 + (lane & 15)];
        b2v[ct]  = b2[ct * 16 + (lane & 15)];
        bd2v[ct] = bd2[ct * 16 + (lane & 15)];
    }
    __syncthreads();  // all waves done reading wd2t; region becomes d2buf

    int4 rc = rec[p];
    int s_my = rc.x, t_my = rc.y;
    RU ra, rb;
    ra.i = rc.z; rb.i = rc.w;
    float x0 = (float)ra.h.x, x1 = (float)ra.h.y, x2 = (float)rb.h.x;

    // ---- LN1 stats via precomputed quadratic form ----
    float t01 = x0 * x1, t02 = x0 * x2, t12 = x1 * x2;
    float sA  = fmaf(x0, cst[10], fmaf(x1, cst[11], fmaf(x2, cst[12], cst[13])));
    float qqA = fmaf(x0 * x0, cst[0], fmaf(x1 * x1, cst[1], x2 * x2 * cst[2]));
    float qqB = fmaf(t01, cst[3], fmaf(t02, cst[4], t12 * cst[5]));
    float qqC = fmaf(x0, cst[6], fmaf(x1, cst[7], x2 * cst[8]));
    float sumsq = fmaf(2.f, qqB + qqC, qqA) + cst[9];
    float mu1 = sA * (1.0f / C);
    float var1 = fmaf(-mu1, mu1, sumsq * (1.0f / C));
    float rs1 = __builtin_amdgcn_rsqf(var1 + 1e-5f);

    // ---- pass B: compute h, LN1+GELU, f16 pairs -> own d2buf row; dot for mu2 ----
    const h2v* wsum2h = (const h2v*)(cst + 16);
    float dot = 0.f;
#pragma unroll
    for (int j2 = 0; j2 < 32; j2++) {
        int j = 2 * j2;
        float hp0 = fmaf(x0, Wd1[j], fmaf(x1, Wd1[C + j], fmaf(x2, Wd1[2 * C + j], bd1[j])));
        float hp1 = fmaf(x0, Wd1[j + 1],
                         fmaf(x1, Wd1[C + j + 1], fmaf(x2, Wd1[2 * C + j + 1], bd1[j + 1])));
        float t0 = fast_gelu(fmaf((hp0 - mu1) * rs1, g1[j], b1[j]));
        float t1 = fast_gelu(fmaf((hp1 - mu1) * rs1, g1[j + 1], b1[j + 1]));
        h2v hv;
        hv.x = (_Float16)t0;
        hv.y = (_Float16)t1;
        sm.s.d2buf[wv][lane][j2] = hv;
        dot = FDOT2(hv, wsum2h[j2], dot);
    }
    sm.s.mu2[wv][lane] = (dot + cst[14]) * (1.0f / C);
    __syncthreads();

    // ---- layer 2: per-wave 64x64x64 GEMM + LN2/GELU epilogue ----
#pragma unroll
    for (int rt = 0; rt < 4; rt++) {
        int arow = rt * 16 + (lane & 15);
        f16x8 af[2];
#pragma unroll
        for (int kh = 0; kh < 2; kh++) {
            const unsigned int* q =
                (const unsigned int*)&sm.s.d2buf[wv][arow][kh * 16 + ((lane >> 4) << 2)];
            FU f;
            f.u[0] = q[0]; f.u[1] = q[1]; f.u[2] = q[2]; f.u[3] = q[3];
            af[kh] = f.h;
        }
        f32x4 acc[4];
#pragma unroll
        for (int ct = 0; ct < 4; ct++) {
            f32x4 z = {0.f, 0.f, 0.f, 0.f};
            z = __builtin_amdgcn_mfma_f32_16x16x32_f16(af[0], bf[2 * ct], z, 0, 0, 0);
            z = __builtin_amdgcn_mfma_f32_16x16x32_f16(af[1], bf[2 * ct + 1], z, 0, 0, 0);
            acc[ct] = z;
        }
#pragma unroll
        for (int reg = 0; reg < 4; reg++) {
            float v0 = acc[0][reg] + bd2v[0];
            float v1 = acc[1][reg] + bd2v[1];
            float v2 = acc[2][reg] + bd2v[2];
            float v3 = acc[3][reg] + bd2v[3];
            float qq = fmaf(v0, v0, fmaf(v1, v1, fmaf(v2, v2, v3 * v3)));
#pragma unroll
            for (int m = 1; m <= 8; m <<= 1) qq += __shfl_xor(qq, m);
            int row = rt * 16 + ((lane >> 4) << 2) + reg;
            float mu = sm.s.mu2[wv][row];
            float var = fmaf(-mu, mu, qq * (1.0f / C));
            float rs = __builtin_amdgcn_rsqf(var + 1e-5f);
            float vv[4] = {v0, v1, v2, v3};
#pragma unroll
            for (int ct = 0; ct < 4; ct++) {
                float v = fast_gelu(fmaf((vv[ct] - mu) * rs, g2v[ct], b2v[ct]));
                float vp = __shfl_xor(v, 1);
                if (!(lane & 1)) {
                    h2v pv;
                    pv.x = (_Float16)v;
                    pv.y = (_Float16)vp;
                    sm.s.d2buf[wv][row][ct * 8 + ((lane & 15) >> 1)] = pv;
                }
            }
        }
    }
    __syncthreads();  // dv rows settled before cross-lane phase-2 reads

    // ---- phase 2: lane = channel; pipelined v23 gathers; w1 on segment change ----
    int cur_t = -1;
    bool owned = false;
    float den_a = 0.f, num_a = 0.f, w1v = 0.f;

    int tin[4];
    h2v v23n[4];
#define PREF(BASE)                                                             \
    {                                                                          \
        _Pragma("unroll")                                                      \
        for (int q = 0; q < 4; q++) {                                          \
            int sq = __shfl(s_my, (BASE) + q);                                 \
            tin[q] = __shfl(t_my, (BASE) + q);                                 \
            v23n[q] = w23h[(size_t)sq * C + lane];                             \
        }                                                                      \
    }
    PREF(0)
    for (int i0 = 0; i0 < 64; i0 += 4) {
        int tic[4];
        h2v v23c[4];
#pragma unroll
        for (int q = 0; q < 4; q++) { tic[q] = tin[q]; v23c[q] = v23n[q]; }
        if (i0 < 60) PREF(i0 + 4)
#pragma unroll
        for (int q = 0; q < 4; q++) {
            int i = i0 + q;
            int ti = tic[q];
            if (ti != cur_t) {
                if (cur_t >= 0) {
                    size_t o = (size_t)cur_t * C + lane;
                    if (owned) out[o] = num_a / den_a;
                    else { unsafeAtomicAdd(&den[o], den_a); unsafeAtomicAdd(&out[o], num_a); }
                }
                cur_t = ti; den_a = 0.f; num_a = 0.f;
                w1v = (float)w1h[(size_t)ti * C + lane];
                int o0 = offsets[ti], o1 = offsets[ti + 1];
                owned = (o0 >= p0) && (o1 <= p0 + 64);
            }
            h2v pr = sm.s.d2buf[wv][i][lane >> 1];
            float dv = (lane & 1) ? (float)pr.y : (float)pr.x;
            h2v v23 = v23c[q];
            float ee = EXP2F(fmaf(dv, LOG2E, w1v) - (float)v23.x);
            den_a += ee;
            num_a = fmaf(ee, (float)v23.y + dv, num_a);
        }
    }
#undef PREF
    {
        size_t o = (size_t)cur_t * C + lane;
        if (owned) out[o] = num_a / den_a;
        else { unsafeAtomicAdd(&den[o], den_a); unsafeAtomicAdd(&out[o], num_a); }
    }
}

// ---------- finalize: divide straddler targets (den > 0) ----------

__global__ __launch_bounds__(256) void finalize(float4* __restrict__ out,
                                                const float4* __restrict__ den) {
    int i = blockIdx.x * 256 + threadIdx.x;
    if (i >= MM * (C / 4)) return;
    float4 dn = den[i];
    if (dn.x == 0.f && dn.y == 0.f && dn.z == 0.f && dn.w == 0.f) return;
    float4 nm = out[i];
    float4 o;
    o.x = (dn.x != 0.f) ? nm.x / dn.x : nm.x;
    o.y = (dn.y != 0.f) ? nm.y / dn.y : nm.y;
    o.z = (dn.z != 0.f) ? nm.z / dn.z : nm.z;
    o.w = (dn.w != 0.f) ? nm.w / dn.w : nm.w;
    out[i] = o;
}

// ---------- launch ----------

extern "C" void kernel_launch(void* const* d_in, const int* in_sizes, int n_in,
                              void* d_out, int out_size, void* d_ws, size_t ws_size,
                              hipStream_t stream) {
    const int*   src  = (const int*)d_in[0];
    const int*   tgt  = (const int*)d_in[1];
    const float* feat = (const float*)d_in[2];
    const float* hood = (const float*)d_in[3];
    const float* Wd1  = (const float*)d_in[4];
    const float* bd1  = (const float*)d_in[5];
    const float* g1   = (const float*)d_in[6];
    const float* b1   = (const float*)d_in[7];
    const float* Wd2  = (const float*)d_in[8];
    const float* bd2  = (const float*)d_in[9];
    const float* g2   = (const float*)d_in[10];
    const float* b2   = (const float*)d_in[11];
    const float* W1   = (const float*)d_in[12];
    const float* W2   = (const float*)d_in[13];
    const float* W3   = (const float*)d_in[14];

    char* ws = (char*)d_ws;
    int4*     rec  = (int4*)ws;              ws += (size_t)EE * 16;
    float*    den  = (float*)ws;             ws += (size_t)MM * C * 4;
    int* counts_cursor = (int*)ws;           ws += 50176 * 4;   // adjacent to den
    h2v*      w23h = (h2v*)ws;               ws += (size_t)MM * C * 4;
    _Float16* w1h  = (_Float16*)ws;          ws += (size_t)MM * C * 2;
    int* offsets = (int*)ws;                 ws += 50432 * 4;
    int* bsum = (int*)ws;                    ws += 256 * 4;
    float* consts = (float*)ws;
    float* out = (float*)d_out;

    // one memset covers den + counts (adjacent); out zeroed separately
    hipMemsetAsync(den, 0, (size_t)MM * C * 4 + 50176 * 4, stream);
    hipMemsetAsync(out, 0, (size_t)MM * C * sizeof(float), stream);

    node_proj_mfma<<<NPB + CNTB, 256, 0, stream>>>(feat, W1, W2, W3, w1h, w23h,
                                                   tgt, counts_cursor);
    scan1<<<NSB, 256, 0, stream>>>(counts_cursor, offsets, bsum);
    scan2<<<1, 256, 0, stream>>>(bsum, Wd1, bd1, Wd2, bd2, consts);
    scan3<<<NSB, 256, 0, stream>>>(offsets, bsum, counts_cursor);
    scatter_kernel<<<(EE + 255) / 256, 256, 0, stream>>>(src, tgt, hood,
                                                         counts_cursor, rec);
    main_kernel<<<NWIN / 4, 256, 0, stream>>>(rec, offsets,
                                              Wd1, bd1, g1, b1, Wd2, bd2, g2, b2,
                                              w1h, w23h, consts, den, out);
    finalize<<<(MM * 16 + 255) / 256, 256, 0, stream>>>((float4*)out, (const float4*)den);
}

// Round 15
// 175.695 us; speedup vs baseline: 1.3495x; 1.2553x over previous
//
#include <hip/hip_runtime.h>

#define MM 50000
#define EE 800000
#define C  64
#define NWIN (EE / 64)   // 12500 windows of 64 sorted edges
#define NPB  391         // ceil(50000/128) node-proj blocks (128 nodes each)
#define CNTB 3125        // count blocks (800000/256)
#define NSB  196         // scan blocks (196*256 = 50176)
#define LOG2E 1.44269504088896f

typedef _Float16 h2v __attribute__((ext_vector_type(2)));
typedef _Float16 f16x8 __attribute__((ext_vector_type(8)));
typedef float f32x4 __attribute__((ext_vector_type(4)));

union FU { unsigned int u[4]; f16x8 h; };
union RU { int i; h2v h; };

#if __has_builtin(__builtin_amdgcn_fdot2)
#define FDOT2(A, B, ACC) __builtin_amdgcn_fdot2((A), (B), (ACC), false)
#else
#define FDOT2(A, B, ACC) fmaf((float)(A).x, (float)(B).x, fmaf((float)(A).y, (float)(B).y, (ACC)))
#endif

// raw v_exp_f32 (D = 2^S0); libm exp2f is an OCML call with edge handling (r13 lesson)
#if __has_builtin(__builtin_amdgcn_exp2f)
#define EXP2F(X) __builtin_amdgcn_exp2f(X)
#else
#define EXP2F(X) __expf((X) * 0.6931471805599453f)
#endif

// ---------- helpers ----------

__device__ __forceinline__ float fast_gelu(float x) {
    // x * sigmoid(1.5957691*(x+0.044715x^3)); exp folded to exp2 (coef *= log2e)
    float x3 = x * x * x;
    float u  = 2.3022082f * fmaf(0.044715f, x3, x);
    float ex = EXP2F(-u);
    float s  = __builtin_amdgcn_rcpf(1.0f + ex);
    return x * s;
}

// ---------- kernel 1: node projections via MFMA, 128 nodes/block + fused count ----------
// Count path ALSO records each edge's intra-target rank (atomicAdd return value)
// so the scatter pass needs no atomics. W1/W2 pre-scaled by log2e.

__global__ __launch_bounds__(256) void node_proj_mfma(
    const float* __restrict__ feat,
    const float* __restrict__ W1, const float* __restrict__ W2,
    const float* __restrict__ W3,
    _Float16* __restrict__ w1h, h2v* __restrict__ w23h,
    const int* __restrict__ tgt, int* __restrict__ counts,
    int* __restrict__ rank) {
    int bid = blockIdx.x;
    if (bid >= NPB) {  // fused edge-count blocks (no barrier taken on this path)
        int e = (bid - NPB) * 256 + threadIdx.x;
        if (e < EE) rank[e] = atomicAdd(&counts[tgt[e]], 1);
        return;
    }
    __shared__ _Float16 Asub[128][72];  // 18.4 KB
    __shared__ _Float16 Bt[192][72];    // 27.6 KB, transposed weights [col][k]
    int tid = threadIdx.x;

    {
        int row = tid >> 1, c0 = (tid & 1) * 32;
        int n = min(bid * 128 + row, MM - 1);
        const float4* s4 = (const float4*)(feat + (size_t)n * C + c0);
#pragma unroll
        for (int q = 0; q < 4; q++) {
            float4 fa = s4[2 * q], fb = s4[2 * q + 1];
            f16x8 v = {(_Float16)fa.x, (_Float16)fa.y, (_Float16)fa.z, (_Float16)fa.w,
                       (_Float16)fb.x, (_Float16)fb.y, (_Float16)fb.z, (_Float16)fb.w};
            *(f16x8*)&Asub[row][c0 + 8 * q] = v;
        }
    }
#pragma unroll
    for (int i = 0; i < 48; i++) {
        int idx = i * 256 + tid;
        int cc = idx & 63;
        int kk = (idx >> 6) & 63;
        int mat = idx >> 12;
        const float* W = (mat == 0) ? W1 : (mat == 1) ? W2 : W3;
        float w = W[kk * 64 + cc];
        if (mat < 2) w *= LOG2E;  // pre-scale logit projections for exp2
        Bt[mat * 64 + cc][kk] = (_Float16)w;
    }
    __syncthreads();

    int wv = tid >> 6, lane = tid & 63;
    int kgrp = (lane >> 4) * 8;
    f16x8 af0[2], af1[2];
#pragma unroll
    for (int rt2 = 0; rt2 < 2; rt2++) {
        int arow = wv * 32 + rt2 * 16 + (lane & 15);
        af0[rt2] = *(const f16x8*)&Asub[arow][kgrp];
        af1[rt2] = *(const f16x8*)&Asub[arow][32 + kgrp];
    }

    f32x4 acc[2][12];
#pragma unroll
    for (int rt2 = 0; rt2 < 2; rt2++)
#pragma unroll
        for (int ct = 0; ct < 12; ct++) acc[rt2][ct] = (f32x4){0.f, 0.f, 0.f, 0.f};

#pragma unroll
    for (int ct = 0; ct < 12; ct++) {
        int bcol = ct * 16 + (lane & 15);
        f16x8 b0 = *(const f16x8*)&Bt[bcol][kgrp];
        f16x8 b1 = *(const f16x8*)&Bt[bcol][32 + kgrp];
#pragma unroll
        for (int rt2 = 0; rt2 < 2; rt2++) {
            acc[rt2][ct] = __builtin_amdgcn_mfma_f32_16x16x32_f16(af0[rt2], b0, acc[rt2][ct], 0, 0, 0);
            acc[rt2][ct] = __builtin_amdgcn_mfma_f32_16x16x32_f16(af1[rt2], b1, acc[rt2][ct], 0, 0, 0);
        }
    }

    int cbase = lane & 15;
#pragma unroll
    for (int rt2 = 0; rt2 < 2; rt2++) {
#pragma unroll
        for (int reg = 0; reg < 4; reg++) {
            int n = bid * 128 + wv * 32 + rt2 * 16 + (lane >> 4) * 4 + reg;
            if (n < MM) {
#pragma unroll
                for (int ct = 0; ct < 4; ct++)
                    w1h[(size_t)n * C + ct * 16 + cbase] = (_Float16)acc[rt2][ct][reg];
#pragma unroll
                for (int ct = 0; ct < 4; ct++) {
                    h2v pv;
                    pv.x = (_Float16)acc[rt2][4 + ct][reg];   // w2 (scaled)
                    pv.y = (_Float16)acc[rt2][8 + ct][reg];   // w3 (unscaled)
                    w23h[(size_t)n * C + ct * 16 + cbase] = pv;
                }
            }
        }
    }
}

// ---------- hierarchical scan + const precompute ----------

__global__ __launch_bounds__(256) void scan1(const int* __restrict__ counts,
                                             int* __restrict__ offsets,
                                             int* __restrict__ bsum) {
    __shared__ int wsum[4];
    int tid = threadIdx.x;
    int lane = tid & 63, wv = tid >> 6;
    int i = blockIdx.x * 256 + tid;
    int orig = counts[i];
    int v = orig;
#pragma unroll
    for (int d = 1; d < 64; d <<= 1) {
        int u = __shfl_up(v, d);
        if (lane >= d) v += u;
    }
    if (lane == 63) wsum[wv] = v;
    __syncthreads();
    int woff = 0;
#pragma unroll
    for (int w = 0; w < 4; w++) woff += (w < wv) ? wsum[w] : 0;
    offsets[i] = woff + v - orig;  // block-local exclusive prefix
    if (tid == 255) bsum[blockIdx.x] = woff + v;
}

// scan of block sums + precompute of LN1 quadratic-form constants and Wd2 row sums.
// consts layout (floats): [0..5]=M00,M11,M22,M01,M02,M12; [6..8]=sum b*w; [9]=sum b^2;
// [10..12]=sum w; [13]=sum b; [14]=sum bd2; [16..47]=wsum2 as 32 h2v pairs.
__global__ __launch_bounds__(256) void scan2(int* __restrict__ bsum,
                                             const float* __restrict__ Wd1,
                                             const float* __restrict__ bd1,
                                             const float* __restrict__ Wd2,
                                             const float* __restrict__ bd2,
                                             float* __restrict__ consts) {
    __shared__ int wsum[4];
    int tid = threadIdx.x;
    int lane = tid & 63, wv = tid >> 6;
    int orig = (tid < NSB) ? bsum[tid] : 0;
    int v = orig;
#pragma unroll
    for (int d = 1; d < 64; d <<= 1) {
        int u = __shfl_up(v, d);
        if (lane >= d) v += u;
    }
    if (lane == 63) wsum[wv] = v;
    __syncthreads();
    int woff = 0;
#pragma unroll
    for (int w = 0; w < 4; w++) woff += (w < wv) ? wsum[w] : 0;
    if (tid < NSB) bsum[tid] = woff + v - orig;  // exclusive

    if (tid < 64) {
        int j = tid;
        float w0 = Wd1[j], w1 = Wd1[64 + j], w2 = Wd1[128 + j], b = bd1[j];
        float q[14] = {w0 * w0, w1 * w1, w2 * w2, w0 * w1, w0 * w2, w1 * w2,
                       b * w0, b * w1, b * w2, b * b, w0, w1, w2, b};
#pragma unroll
        for (int m = 1; m < 64; m <<= 1) {
#pragma unroll
            for (int k = 0; k < 14; k++) q[k] += __shfl_xor(q[k], m);
        }
        if (j == 0) {
#pragma unroll
            for (int k = 0; k < 14; k++) consts[k] = q[k];
        }
    } else if (tid < 128) {
        int k = tid - 64;
        float s = 0.f;
        const float4* r4 = (const float4*)(Wd2 + k * 64);
#pragma unroll
        for (int q4 = 0; q4 < 16; q4++) {
            float4 f = r4[q4];
            s += (f.x + f.y) + (f.z + f.w);
        }
        float sp = __shfl_xor(s, 1);
        if (!(k & 1)) {
            h2v pv;
            pv.x = (_Float16)s;
            pv.y = (_Float16)sp;
            ((h2v*)(consts + 16))[k >> 1] = pv;
        }
        float b = bd2[k];
#pragma unroll
        for (int m = 1; m < 64; m <<= 1) b += __shfl_xor(b, m);
        if (k == 0) consts[14] = b;
    }
}

__global__ __launch_bounds__(256) void scan3(int* __restrict__ offsets,
                                             const int* __restrict__ bsum) {
    int i = blockIdx.x * 256 + threadIdx.x;
    offsets[i] += bsum[blockIdx.x];
}

// ---------- scatter: NO atomics — pos = offsets[t] + rank[e] ----------

__global__ __launch_bounds__(256) void scatter_kernel(
    const int* __restrict__ src, const int* __restrict__ tgt,
    const float* __restrict__ hood, const int* __restrict__ rank,
    const int* __restrict__ offsets, int4* __restrict__ rec) {
    int e = blockIdx.x * 256 + threadIdx.x;
    if (e >= EE) return;
    int t = tgt[e];
    float x0 = hood[3 * e], x1 = hood[3 * e + 1], x2 = hood[3 * e + 2];
    int pos = offsets[t] + rank[e];
    RU a, b;
    a.h.x = (_Float16)x0; a.h.y = (_Float16)x1;
    b.h.x = (_Float16)x2; b.h.y = (_Float16)0.f;
    rec[pos] = make_int4(src[e], t, a.i, b.i);
}

// ---------- main: r14 byte-identical (proven 108.9 us) ----------

union SMem {
    _Float16 wd2t[64][66];   // 8448 B, live only until bf[] hoisted to regs
    struct {
        h2v d2buf[4][64][33];  // 33792 B, per-wave h staging then final dv
        float mu2[4][64];      // 1024 B, per-edge pre-LN2 mean
    } s;
};

__global__ __launch_bounds__(256, 4) void main_kernel(
    const int4* __restrict__ rec, const int* __restrict__ offsets,
    const float* __restrict__ Wd1, const float* __restrict__ bd1,
    const float* __restrict__ g1, const float* __restrict__ b1,
    const float* __restrict__ Wd2, const float* __restrict__ bd2,
    const float* __restrict__ g2, const float* __restrict__ b2,
    const _Float16* __restrict__ w1h, const h2v* __restrict__ w23h,
    const float* __restrict__ cst,
    float* __restrict__ den, float* __restrict__ out) {
    __shared__ SMem sm;
    int tid = threadIdx.x;
    int wv = tid >> 6, lane = tid & 63;
    int p0 = blockIdx.x * 256 + wv * 64;
    int p = p0 + lane;

#pragma unroll
    for (int i = 0; i < 16; i++) {
        int idx = i * 256 + tid;
        int j = idx & 63, k = idx >> 6;
        sm.wd2t[j][k] = (_Float16)Wd2[k * 64 + j];
    }
    __syncthreads();

    f16x8 bf[8];
#pragma unroll
    for (int ct = 0; ct < 4; ct++) {
#pragma unroll
        for (int kh = 0; kh < 2; kh++) {
            const unsigned int* q =
                (const unsigned int*)&sm.wd2t[ct * 16 + (lane & 15)][kh * 32 + ((lane >> 4) << 3)];
            FU f;
            f.u[0] = q[0]; f.u[1] = q[1]; f.u[2] = q[2]; f.u[3] = q[3];
            bf[ct * 2 + kh] = f.h;
        }
    }
    float g2v[4], b2v[4], bd2v[4];
#pragma unroll
    for (int ct = 0; ct < 4; ct++) {
        g2v[ct]  = g2[ct * 16 + (lane & 15)];
        b2v[ct]  = b2[ct * 16 + (lane & 15)];
        bd2v[ct] = bd2[ct * 16 + (lane & 15)];
    }
    __syncthreads();  // all waves done reading wd2t; region becomes d2buf

    int4 rc = rec[p];
    int s_my = rc.x, t_my = rc.y;
    RU ra, rb;
    ra.i = rc.z; rb.i = rc.w;
    float x0 = (float)ra.h.x, x1 = (float)ra.h.y, x2 = (float)rb.h.x;

    // ---- LN1 stats via precomputed quadratic form ----
    float t01 = x0 * x1, t02 = x0 * x2, t12 = x1 * x2;
    float sA  = fmaf(x0, cst[10], fmaf(x1, cst[11], fmaf(x2, cst[12], cst[13])));
    float qqA = fmaf(x0 * x0, cst[0], fmaf(x1 * x1, cst[1], x2 * x2 * cst[2]));
    float qqB = fmaf(t01, cst[3], fmaf(t02, cst[4], t12 * cst[5]));
    float qqC = fmaf(x0, cst[6], fmaf(x1, cst[7], x2 * cst[8]));
    float sumsq = fmaf(2.f, qqB + qqC, qqA) + cst[9];
    float mu1 = sA * (1.0f / C);
    float var1 = fmaf(-mu1, mu1, sumsq * (1.0f / C));
    float rs1 = __builtin_amdgcn_rsqf(var1 + 1e-5f);

    // ---- pass B: compute h, LN1+GELU, f16 pairs -> own d2buf row; dot for mu2 ----
    const h2v* wsum2h = (const h2v*)(cst + 16);
    float dot = 0.f;
#pragma unroll
    for (int j2 = 0; j2 < 32; j2++) {
        int j = 2 * j2;
        float hp0 = fmaf(x0, Wd1[j], fmaf(x1, Wd1[C + j], fmaf(x2, Wd1[2 * C + j], bd1[j])));
        float hp1 = fmaf(x0, Wd1[j + 1],
                         fmaf(x1, Wd1[C + j + 1], fmaf(x2, Wd1[2 * C + j + 1], bd1[j + 1])));
        float t0 = fast_gelu(fmaf((hp0 - mu1) * rs1, g1[j], b1[j]));
        float t1 = fast_gelu(fmaf((hp1 - mu1) * rs1, g1[j + 1], b1[j + 1]));
        h2v hv;
        hv.x = (_Float16)t0;
        hv.y = (_Float16)t1;
        sm.s.d2buf[wv][lane][j2] = hv;
        dot = FDOT2(hv, wsum2h[j2], dot);
    }
    sm.s.mu2[wv][lane] = (dot + cst[14]) * (1.0f / C);
    __syncthreads();

    // ---- layer 2: per-wave 64x64x64 GEMM + LN2/GELU epilogue ----
#pragma unroll
    for (int rt = 0; rt < 4; rt++) {
        int arow = rt * 16 + (lane & 15);
        f16x8 af[2];
#pragma unroll
        for (int kh = 0; kh < 2; kh++) {
            const unsigned int* q =
                (const unsigned int*)&sm.s.d2buf[wv][arow][kh * 16 + ((lane >> 4) << 2)];
            FU f;
            f.u[0] = q[0]; f.u[1] = q[1]; f.u[2] = q[2]; f.u[3] = q[3];
            af[kh] = f.h;
        }
        f32x4 acc[4];
#pragma unroll
        for (int ct = 0; ct < 4; ct++) {
            f32x4 z = {0.f, 0.f, 0.f, 0.f};
            z = __builtin_amdgcn_mfma_f32_16x16x32_f16(af[0], bf[2 * ct], z, 0, 0, 0);
            z = __builtin_amdgcn_mfma_f32_16x16x32_f16(af[1], bf[2 * ct + 1], z, 0, 0, 0);
            acc[ct] = z;
        }
#pragma unroll
        for (int reg = 0; reg < 4; reg++) {
            float v0 = acc[0][reg] + bd2v[0];
            float v1 = acc[1][reg] + bd2v[1];
            float v2 = acc[2][reg] + bd2v[2];
            float v3 = acc[3][reg] + bd2v[3];
            float qq = fmaf(v0, v0, fmaf(v1, v1, fmaf(v2, v2, v3 * v3)));
#pragma unroll
            for (int m = 1; m <= 8; m <<= 1) qq += __shfl_xor(qq, m);
            int row = rt * 16 + ((lane >> 4) << 2) + reg;
            float mu = sm.s.mu2[wv][row];
            float var = fmaf(-mu, mu, qq * (1.0f / C));
            float rs = __builtin_amdgcn_rsqf(var + 1e-5f);
            float vv[4] = {v0, v1, v2, v3};
#pragma unroll
            for (int ct = 0; ct < 4; ct++) {
                float v = fast_gelu(fmaf((vv[ct] - mu) * rs, g2v[ct], b2v[ct]));
                float vp = __shfl_xor(v, 1);
                if (!(lane & 1)) {
                    h2v pv;
                    pv.x = (_Float16)v;
                    pv.y = (_Float16)vp;
                    sm.s.d2buf[wv][row][ct * 8 + ((lane & 15) >> 1)] = pv;
                }
            }
        }
    }
    __syncthreads();  // dv rows settled before cross-lane phase-2 reads

    // ---- phase 2: lane = channel; pipelined v23 gathers; w1 on segment change ----
    int cur_t = -1;
    bool owned = false;
    float den_a = 0.f, num_a = 0.f, w1v = 0.f;

    int tin[4];
    h2v v23n[4];
#define PREF(BASE)                                                             \
    {                                                                          \
        _Pragma("unroll")                                                      \
        for (int q = 0; q < 4; q++) {                                          \
            int sq = __shfl(s_my, (BASE) + q);                                 \
            tin[q] = __shfl(t_my, (BASE) + q);                                 \
            v23n[q] = w23h[(size_t)sq * C + lane];                             \
        }                                                                      \
    }
    PREF(0)
    for (int i0 = 0; i0 < 64; i0 += 4) {
        int tic[4];
        h2v v23c[4];
#pragma unroll
        for (int q = 0; q < 4; q++) { tic[q] = tin[q]; v23c[q] = v23n[q]; }
        if (i0 < 60) PREF(i0 + 4)
#pragma unroll
        for (int q = 0; q < 4; q++) {
            int i = i0 + q;
            int ti = tic[q];
            if (ti != cur_t) {
                if (cur_t >= 0) {
                    size_t o = (size_t)cur_t * C + lane;
                    if (owned) out[o] = num_a / den_a;
                    else { unsafeAtomicAdd(&den[o], den_a); unsafeAtomicAdd(&out[o], num_a); }
                }
                cur_t = ti; den_a = 0.f; num_a = 0.f;
                w1v = (float)w1h[(size_t)ti * C + lane];
                int o0 = offsets[ti], o1 = offsets[ti + 1];
                owned = (o0 >= p0) && (o1 <= p0 + 64);
            }
            h2v pr = sm.s.d2buf[wv][i][lane >> 1];
            float dv = (lane & 1) ? (float)pr.y : (float)pr.x;
            h2v v23 = v23c[q];
            float ee = EXP2F(fmaf(dv, LOG2E, w1v) - (float)v23.x);
            den_a += ee;
            num_a = fmaf(ee, (float)v23.y + dv, num_a);
        }
    }
#undef PREF
    {
        size_t o = (size_t)cur_t * C + lane;
        if (owned) out[o] = num_a / den_a;
        else { unsafeAtomicAdd(&den[o], den_a); unsafeAtomicAdd(&out[o], num_a); }
    }
}

// ---------- finalize: divide straddler targets (den > 0) ----------

__global__ __launch_bounds__(256) void finalize(float4* __restrict__ out,
                                                const float4* __restrict__ den) {
    int i = blockIdx.x * 256 + threadIdx.x;
    if (i >= MM * (C / 4)) return;
    float4 dn = den[i];
    if (dn.x == 0.f && dn.y == 0.f && dn.z == 0.f && dn.w == 0.f) return;
    float4 nm = out[i];
    float4 o;
    o.x = (dn.x != 0.f) ? nm.x / dn.x : nm.x;
    o.y = (dn.y != 0.f) ? nm.y / dn.y : nm.y;
    o.z = (dn.z != 0.f) ? nm.z / dn.z : nm.z;
    o.w = (dn.w != 0.f) ? nm.w / dn.w : nm.w;
    out[i] = o;
}

// ---------- launch ----------

extern "C" void kernel_launch(void* const* d_in, const int* in_sizes, int n_in,
                              void* d_out, int out_size, void* d_ws, size_t ws_size,
                              hipStream_t stream) {
    const int*   src  = (const int*)d_in[0];
    const int*   tgt  = (const int*)d_in[1];
    const float* feat = (const float*)d_in[2];
    const float* hood = (const float*)d_in[3];
    const float* Wd1  = (const float*)d_in[4];
    const float* bd1  = (const float*)d_in[5];
    const float* g1   = (const float*)d_in[6];
    const float* b1   = (const float*)d_in[7];
    const float* Wd2  = (const float*)d_in[8];
    const float* bd2  = (const float*)d_in[9];
    const float* g2   = (const float*)d_in[10];
    const float* b2   = (const float*)d_in[11];
    const float* W1   = (const float*)d_in[12];
    const float* W2   = (const float*)d_in[13];
    const float* W3   = (const float*)d_in[14];

    char* ws = (char*)d_ws;
    int4*     rec  = (int4*)ws;              ws += (size_t)EE * 16;
    float*    den  = (float*)ws;             ws += (size_t)MM * C * 4;
    int* counts = (int*)ws;                  ws += 50176 * 4;   // adjacent to den
    h2v*      w23h = (h2v*)ws;               ws += (size_t)MM * C * 4;
    _Float16* w1h  = (_Float16*)ws;          ws += (size_t)MM * C * 2;
    int* offsets = (int*)ws;                 ws += 50432 * 4;
    int* bsum = (int*)ws;                    ws += 256 * 4;
    float* consts = (float*)ws;              ws += 64 * 4;
    int* rank = (int*)ws;
    float* out = (float*)d_out;

    // one memset covers den + counts (adjacent); out zeroed separately
    hipMemsetAsync(den, 0, (size_t)MM * C * 4 + 50176 * 4, stream);
    hipMemsetAsync(out, 0, (size_t)MM * C * sizeof(float), stream);

    node_proj_mfma<<<NPB + CNTB, 256, 0, stream>>>(feat, W1, W2, W3, w1h, w23h,
                                                   tgt, counts, rank);
    scan1<<<NSB, 256, 0, stream>>>(counts, offsets, bsum);
    scan2<<<1, 256, 0, stream>>>(bsum, Wd1, bd1, Wd2, bd2, consts);
    scan3<<<NSB, 256, 0, stream>>>(offsets, bsum);
    scatter_kernel<<<(EE + 255) / 256, 256, 0, stream>>>(src, tgt, hood, rank,
                                                         offsets, rec);
    main_kernel<<<NWIN / 4, 256, 0, stream>>>(rec, offsets,
                                              Wd1, bd1, g1, b1, Wd2, bd2, g2, b2,
                                              w1h, w23h, consts, den, out);
    finalize<<<(MM * 16 + 255) / 256, 256, 0, stream>>>((float4*)out, (const float4*)den);
}